// Round 4
// baseline (1403.885 us; speedup 1.0000x reference)
//
#include <hip/hip_runtime.h>
#include <cstddef>

// ---------------------------------------------------------------------------
// GraphSAGE 2-layer (mean aggregator), fp32, MI355X.
//
// out_l = act( mean_agg @ W_l^T + self @ W_r^T + b )
// Reformulated per layer as ONE GEMM with K=256:
//   A_virtual[M][256] = [ agg*inv_cnt | self ]
//   WT[256][128]      = [ W_l^T ; W_r^T ]   (WT[k][c] = W_l[c][k] or W_r[c][k-128])
//
// edge_index is staged int32 (harness contract), layout [2][E]:
//   src = ei[e], dst = ei[E+e].
// ---------------------------------------------------------------------------

__global__ void zero_kernel(float4* __restrict__ p, long n4) {
    long i = (long)blockIdx.x * blockDim.x + threadIdx.x;
    long stride = (long)gridDim.x * blockDim.x;
    float4 z = {0.f, 0.f, 0.f, 0.f};
    for (; i < n4; i += stride) p[i] = z;
}

// Build stacked transpose: out[256][128], out[k][c] = k<128 ? Wl[c][k] : Wr[c][k-128]
__global__ void transpose_stack(const float* __restrict__ Wl,
                                const float* __restrict__ Wr,
                                float* __restrict__ out) {
    int idx = blockIdx.x * 256 + threadIdx.x;   // 0..32767
    int k = idx >> 7, c = idx & 127;
    out[idx] = (k < 128) ? Wl[c * 128 + k] : Wr[c * 128 + (k - 128)];
}

__global__ void invcnt_kernel(float* __restrict__ cnt, int M) {
    int i = blockIdx.x * 256 + threadIdx.x;
    if (i < M) cnt[i] = 1.0f / fmaxf(cnt[i], 1.0f);
}

// One 64-lane wave per edge; lane handles 2 channels (float2).
__global__ void aggregate_kernel(const float* __restrict__ feat,
                                 const int* __restrict__ ei,
                                 float* __restrict__ agg,
                                 float* __restrict__ cnt,
                                 int E, int doCount) {
    int e = (blockIdx.x << 2) + (threadIdx.x >> 6);
    if (e >= E) return;
    int lane = threadIdx.x & 63;
    int s = ei[e];
    int d = ei[E + e];
    const float2 v = *reinterpret_cast<const float2*>(&feat[(size_t)s * 128 + lane * 2]);
    float* dp = &agg[(size_t)d * 128 + lane * 2];
    atomicAdd(dp, v.x);
    atomicAdd(dp + 1, v.y);
    if (doCount && lane == 0) atomicAdd(&cnt[d], 1.0f);
}

// Single-GEMM SAGE layer: out = act(A_virtual @ WT + bias)
// Tile: 128 rows x 128 cols, K=256, KT=32. 256 threads, 8x8 cells each.
template <bool RELU>
__global__ __launch_bounds__(256, 2)
void sage_gemm(const float* __restrict__ agg, const float* __restrict__ invc,
               const float* __restrict__ selfF, const float* __restrict__ WT,
               const float* __restrict__ bias,
               float* __restrict__ out, int M) {
    __shared__ float sW[32][128];    // 16 KiB
    __shared__ float sA[32][136];    // 17.4 KiB (pad 136 keeps writes 2-way max)

    const int tid  = threadIdx.x;
    const int row0 = blockIdx.x * 128;
    const int r0 = (tid >> 4) * 8;   // 0..120
    const int c0 = (tid & 15) * 8;   // 0..120

    // staging map: thread -> (row tr, k-chunk tk of 16)
    const int tr = tid >> 1;         // 0..127
    const int tk = (tid & 1) * 16;   // 0 or 16
    const int arow = row0 + tr;
    const bool avalid = arow < M;
    const float inv_r = avalid ? invc[arow] : 0.0f;

    float acc[8][8];
#pragma unroll
    for (int i = 0; i < 8; i++)
#pragma unroll
        for (int j = 0; j < 8; j++) acc[i][j] = 0.0f;

    const float4* WT4 = reinterpret_cast<const float4*>(WT);
    float4* sW4 = reinterpret_cast<float4*>(&sW[0][0]);

    for (int k0 = 0; k0 < 256; k0 += 32) {
        __syncthreads();
        // stage weight tile: WT rows k0..k0+31 (32 float4 per row)
#pragma unroll
        for (int i = 0; i < 4; i++)
            sW4[tid + i * 256] = WT4[k0 * 32 + tid + i * 256];

        // stage A tile (transposed into sA[k][row]); k0<128 -> mean path
        float4 v[4];
        if (avalid) {
            const float* src;
            float scale;
            if (k0 < 128) { src = agg   + (size_t)arow * 128 + (k0 + tk);       scale = inv_r; }
        else          { src = selfF + (size_t)arow * 128 + (k0 - 128 + tk); scale = 1.0f;  }
#pragma unroll
            for (int i = 0; i < 4; i++) {
                v[i] = *reinterpret_cast<const float4*>(src + i * 4);
                v[i].x *= scale; v[i].y *= scale; v[i].z *= scale; v[i].w *= scale;
            }
        } else {
#pragma unroll
            for (int i = 0; i < 4; i++) v[i] = {0.f, 0.f, 0.f, 0.f};
        }
#pragma unroll
        for (int i = 0; i < 4; i++) {
            sA[tk + i * 4 + 0][tr] = v[i].x;
            sA[tk + i * 4 + 1][tr] = v[i].y;
            sA[tk + i * 4 + 2][tr] = v[i].z;
            sA[tk + i * 4 + 3][tr] = v[i].w;
        }
        __syncthreads();

#pragma unroll
        for (int k = 0; k < 32; k++) {
            float4 a0 = *reinterpret_cast<const float4*>(&sA[k][r0]);
            float4 a1 = *reinterpret_cast<const float4*>(&sA[k][r0 + 4]);
            float4 w0 = *reinterpret_cast<const float4*>(&sW[k][c0]);
            float4 w1 = *reinterpret_cast<const float4*>(&sW[k][c0 + 4]);
            float am[8] = {a0.x, a0.y, a0.z, a0.w, a1.x, a1.y, a1.z, a1.w};
            float wv[8] = {w0.x, w0.y, w0.z, w0.w, w1.x, w1.y, w1.z, w1.w};
#pragma unroll
            for (int i = 0; i < 8; i++)
#pragma unroll
                for (int j = 0; j < 8; j++)
                    acc[i][j] += am[i] * wv[j];
        }
    }

    float4 b0 = *reinterpret_cast<const float4*>(&bias[c0]);
    float4 b1 = *reinterpret_cast<const float4*>(&bias[c0 + 4]);
    float bb[8] = {b0.x, b0.y, b0.z, b0.w, b1.x, b1.y, b1.z, b1.w};
#pragma unroll
    for (int i = 0; i < 8; i++) {
        int row = row0 + r0 + i;
        if (row < M) {
            float o[8];
#pragma unroll
            for (int j = 0; j < 8; j++) {
                o[j] = acc[i][j] + bb[j];
                if (RELU) o[j] = fmaxf(o[j], 0.0f);
            }
            float4 o0 = {o[0], o[1], o[2], o[3]};
            float4 o1 = {o[4], o[5], o[6], o[7]};
            *reinterpret_cast<float4*>(&out[(size_t)row * 128 + c0])     = o0;
            *reinterpret_cast<float4*>(&out[(size_t)row * 128 + c0 + 4]) = o1;
        }
    }
}

extern "C" void kernel_launch(void* const* d_in, const int* in_sizes, int n_in,
                              void* d_out, int out_size, void* d_ws, size_t ws_size,
                              hipStream_t stream) {
    const float* x   = (const float*)d_in[0];
    const int*   ei  = (const int*)d_in[1];      // int32 per harness contract
    const float* W1l = (const float*)d_in[2];
    const float* W1r = (const float*)d_in[3];
    const float* b1  = (const float*)d_in[4];
    const float* W2l = (const float*)d_in[5];
    const float* W2r = (const float*)d_in[6];
    const float* b2  = (const float*)d_in[7];
    float* out = (float*)d_out;

    const int M = in_sizes[0] / 128;
    const int E = in_sizes[1] / 2;
    const size_t featBytes = (size_t)M * 128 * sizeof(float);
    const size_t cntB = ((size_t)M * sizeof(float) + 511) & ~(size_t)511;

    char* ws = (char*)d_ws;
    float* cnt = (float*)ws;
    float* agg = (float*)(ws + cntB);
    float* h   = (float*)(ws + cntB + featBytes);
    float* wt1 = (float*)(ws + cntB + 2 * featBytes);           // 256x128
    float* wt2 = wt1 + 256 * 128;                               // 256x128

    // 1. stacked weight transposes
    transpose_stack<<<128, 256, 0, stream>>>(W1l, W1r, wt1);
    transpose_stack<<<128, 256, 0, stream>>>(W2l, W2r, wt2);

    // 2. zero cnt + agg
    zero_kernel<<<2048, 256, 0, stream>>>((float4*)ws, (long)((cntB + featBytes) / 16));

    // 3. layer-1 aggregate (+ degree count)
    aggregate_kernel<<<(E + 3) / 4, 256, 0, stream>>>(x, ei, agg, cnt, E, 1);

    // 4. cnt -> 1/max(cnt,1)
    invcnt_kernel<<<(M + 255) / 256, 256, 0, stream>>>(cnt, M);

    // 5. gemm1 -> h (relu)
    sage_gemm<true><<<(M + 127) / 128, 256, 0, stream>>>(agg, cnt, x, wt1, b1, h, M);

    // 6. zero agg; layer-2 aggregate
    zero_kernel<<<2048, 256, 0, stream>>>((float4*)agg, (long)(featBytes / 16));
    aggregate_kernel<<<(E + 3) / 4, 256, 0, stream>>>(h, ei, agg, cnt, E, 0);

    // 7. gemm2 -> out (no relu)
    sage_gemm<false><<<(M + 127) / 128, 256, 0, stream>>>(agg, cnt, h, wt2, b2, out, M);
}

// Round 5
// 514.154 us; speedup vs baseline: 2.7305x; 2.7305x over previous
//
#include <hip/hip_runtime.h>
#include <cstddef>

// ---------------------------------------------------------------------------
// GraphSAGE 2-layer (mean aggregator), fp32, MI355X.
//
// Round 4 -> 5 change: atomic scatter aggregation (554us/dispatch, 660MB of
// L2-RMW write-through) replaced by CSR counting-sort + per-node gather that
// writes the MEAN directly (no fp atomics, no invcnt pass, no agg zeroing).
// CSR is built once per call and reused by both layers.
//
// Pipeline:
//   1. transpose_stack x2 (weights -> WT[256][128] stacked [Wl^T;Wr^T])
//   2. zero histogram; hist(dst); scan1/2/3 -> rowStart + cursor
//   3. scatter: csr_src[pos] = src  (pos via int atomic on cursor)
//   4. csr_aggregate: mean[n] = sum(x[csr[beg..end]]) / max(deg,1)
//   5. gemm1: h = relu([mean|x] @ WT1 + b1)
//   6. csr_aggregate on h -> mean
//   7. gemm2: out = [mean|h] @ WT2 + b2
//
// edge_index staged int32 (harness contract), [2][E]: src=ei[e], dst=ei[E+e].
// ---------------------------------------------------------------------------

__global__ void zero_kernel(float4* __restrict__ p, long n4) {
    long i = (long)blockIdx.x * blockDim.x + threadIdx.x;
    long stride = (long)gridDim.x * blockDim.x;
    float4 z = {0.f, 0.f, 0.f, 0.f};
    for (; i < n4; i += stride) p[i] = z;
}

__global__ void transpose_stack(const float* __restrict__ Wl,
                                const float* __restrict__ Wr,
                                float* __restrict__ out) {
    int idx = blockIdx.x * 256 + threadIdx.x;   // 0..32767
    int k = idx >> 7, c = idx & 127;
    out[idx] = (k < 128) ? Wl[c * 128 + k] : Wr[c * 128 + (k - 128)];
}

// ---------------- CSR build ----------------

__global__ void hist_kernel(const int* __restrict__ ei, int* __restrict__ cnt, int E) {
    int e = blockIdx.x * 256 + threadIdx.x;
    if (e < E) atomicAdd(&cnt[ei[E + e]], 1);
}

// Phase 1: per-1024-chunk sums
__global__ void scan1(const int* __restrict__ cnt, int* __restrict__ blockSums, int M) {
    __shared__ int red[256];
    const int t = threadIdx.x;
    const int base = blockIdx.x * 1024 + t * 4;
    int s = 0;
#pragma unroll
    for (int i = 0; i < 4; i++) { int idx = base + i; if (idx < M) s += cnt[idx]; }
    red[t] = s; __syncthreads();
    for (int off = 128; off > 0; off >>= 1) {
        if (t < off) red[t] += red[t + off];
        __syncthreads();
    }
    if (t == 0) blockSums[blockIdx.x] = red[0];
}

// Phase 2: exclusive scan of blockSums (NB <= 256), one block
__global__ void scan2(int* __restrict__ bs, int NB) {
    __shared__ int tmp[256];
    const int t = threadIdx.x;
    int v = (t < NB) ? bs[t] : 0;
    tmp[t] = v; __syncthreads();
    for (int off = 1; off < 256; off <<= 1) {
        int add = (t >= off) ? tmp[t - off] : 0;
        __syncthreads();
        tmp[t] += add;
        __syncthreads();
    }
    if (t < NB) bs[t] = tmp[t] - v;   // exclusive
}

// Phase 3: full exclusive scan -> rowStart (+ copy to cursor, + rowStart[M])
__global__ void scan3(const int* __restrict__ cnt, const int* __restrict__ blockSums,
                      int* __restrict__ rowStart, int* __restrict__ cursor, int M) {
    __shared__ int tsum[256];
    const int t = threadIdx.x;
    const int base = blockIdx.x * 1024 + t * 4;
    int v[4];
#pragma unroll
    for (int i = 0; i < 4; i++) v[i] = (base + i < M) ? cnt[base + i] : 0;
    const int s = v[0] + v[1] + v[2] + v[3];
    tsum[t] = s; __syncthreads();
    for (int off = 1; off < 256; off <<= 1) {
        int add = (t >= off) ? tsum[t - off] : 0;
        __syncthreads();
        tsum[t] += add;
        __syncthreads();
    }
    int rs = blockSums[blockIdx.x] + (tsum[t] - s);   // exclusive prefix
#pragma unroll
    for (int i = 0; i < 4; i++) {
        int idx = base + i;
        if (idx < M) {
            rowStart[idx] = rs;
            cursor[idx]   = rs;
            rs += v[i];
            if (idx == M - 1) rowStart[M] = rs;
        }
    }
}

__global__ void scatter_kernel(const int* __restrict__ ei, int* __restrict__ cursor,
                               int* __restrict__ csr, int E) {
    int e = blockIdx.x * 256 + threadIdx.x;
    if (e < E) {
        int d = ei[E + e];
        int pos = atomicAdd(&cursor[d], 1);
        csr[pos] = ei[e];
    }
}

// ---------------- mean aggregation (gather) ----------------
// One 64-lane wave per node; lane owns 2 channels (float2 = 512B/wave row).
__global__ void csr_aggregate(const float* __restrict__ feat,
                              const int* __restrict__ rowStart,
                              const int* __restrict__ csr,
                              float* __restrict__ mean, int M) {
    int n = blockIdx.x * (blockDim.x >> 6) + (threadIdx.x >> 6);
    if (n >= M) return;
    const int lane = threadIdx.x & 63;
    const int beg = rowStart[n], end = rowStart[n + 1];
    const int deg = end - beg;

    // preload up to 64 neighbor ids (one per lane), broadcast via shfl
    int myidx = (beg + lane < end) ? csr[beg + lane] : 0;
    float2 acc = {0.f, 0.f};
    const int K = deg < 64 ? deg : 64;
    for (int p = 0; p < K; p++) {
        int s = __shfl(myidx, p);
        const float2 v = *reinterpret_cast<const float2*>(&feat[(size_t)s * 128 + lane * 2]);
        acc.x += v.x; acc.y += v.y;
    }
    for (int q = beg + 64; q < end; q++) {          // rare tail (deg > 64)
        int s = csr[q];
        const float2 v = *reinterpret_cast<const float2*>(&feat[(size_t)s * 128 + lane * 2]);
        acc.x += v.x; acc.y += v.y;
    }
    const float inv = 1.0f / fmaxf((float)deg, 1.0f);
    acc.x *= inv; acc.y *= inv;
    *reinterpret_cast<float2*>(&mean[(size_t)n * 128 + lane * 2]) = acc;
}

// ---------------- fused dual GEMM (K=256) ----------------
// out = act([mean | self] @ WT + bias), WT[256][128] stacked.
// Tile 128x128, KT=32, 256 threads, 8x8 cells/thread.
template <bool RELU>
__global__ __launch_bounds__(256, 2)
void sage_gemm(const float* __restrict__ mean,
               const float* __restrict__ selfF, const float* __restrict__ WT,
               const float* __restrict__ bias,
               float* __restrict__ out, int M) {
    __shared__ float sW[32][128];
    __shared__ float sA[32][136];

    const int tid  = threadIdx.x;
    const int row0 = blockIdx.x * 128;
    const int r0 = (tid >> 4) * 8;
    const int c0 = (tid & 15) * 8;

    const int tr = tid >> 1;         // staging row 0..127
    const int tk = (tid & 1) * 16;   // k-chunk 0 or 16
    const int arow = row0 + tr;
    const bool avalid = arow < M;

    float acc[8][8];
#pragma unroll
    for (int i = 0; i < 8; i++)
#pragma unroll
        for (int j = 0; j < 8; j++) acc[i][j] = 0.0f;

    const float4* WT4 = reinterpret_cast<const float4*>(WT);
    float4* sW4 = reinterpret_cast<float4*>(&sW[0][0]);

    for (int k0 = 0; k0 < 256; k0 += 32) {
        __syncthreads();
#pragma unroll
        for (int i = 0; i < 4; i++)
            sW4[tid + i * 256] = WT4[k0 * 32 + tid + i * 256];

        float4 v[4];
        if (avalid) {
            const float* src = (k0 < 128)
                ? (mean  + (size_t)arow * 128 + (k0 + tk))
                : (selfF + (size_t)arow * 128 + (k0 - 128 + tk));
#pragma unroll
            for (int i = 0; i < 4; i++)
                v[i] = *reinterpret_cast<const float4*>(src + i * 4);
        } else {
#pragma unroll
            for (int i = 0; i < 4; i++) v[i] = {0.f, 0.f, 0.f, 0.f};
        }
#pragma unroll
        for (int i = 0; i < 4; i++) {
            sA[tk + i * 4 + 0][tr] = v[i].x;
            sA[tk + i * 4 + 1][tr] = v[i].y;
            sA[tk + i * 4 + 2][tr] = v[i].z;
            sA[tk + i * 4 + 3][tr] = v[i].w;
        }
        __syncthreads();

#pragma unroll
        for (int k = 0; k < 32; k++) {
            float4 a0 = *reinterpret_cast<const float4*>(&sA[k][r0]);
            float4 a1 = *reinterpret_cast<const float4*>(&sA[k][r0 + 4]);
            float4 w0 = *reinterpret_cast<const float4*>(&sW[k][c0]);
            float4 w1 = *reinterpret_cast<const float4*>(&sW[k][c0 + 4]);
            float am[8] = {a0.x, a0.y, a0.z, a0.w, a1.x, a1.y, a1.z, a1.w};
            float wv[8] = {w0.x, w0.y, w0.z, w0.w, w1.x, w1.y, w1.z, w1.w};
#pragma unroll
            for (int i = 0; i < 8; i++)
#pragma unroll
                for (int j = 0; j < 8; j++)
                    acc[i][j] += am[i] * wv[j];
        }
    }

    float4 b0 = *reinterpret_cast<const float4*>(&bias[c0]);
    float4 b1 = *reinterpret_cast<const float4*>(&bias[c0 + 4]);
    float bb[8] = {b0.x, b0.y, b0.z, b0.w, b1.x, b1.y, b1.z, b1.w};
#pragma unroll
    for (int i = 0; i < 8; i++) {
        int row = row0 + r0 + i;
        if (row < M) {
            float o[8];
#pragma unroll
            for (int j = 0; j < 8; j++) {
                o[j] = acc[i][j] + bb[j];
                if (RELU) o[j] = fmaxf(o[j], 0.0f);
            }
            float4 o0 = {o[0], o[1], o[2], o[3]};
            float4 o1 = {o[4], o[5], o[6], o[7]};
            *reinterpret_cast<float4*>(&out[(size_t)row * 128 + c0])     = o0;
            *reinterpret_cast<float4*>(&out[(size_t)row * 128 + c0 + 4]) = o1;
        }
    }
}

extern "C" void kernel_launch(void* const* d_in, const int* in_sizes, int n_in,
                              void* d_out, int out_size, void* d_ws, size_t ws_size,
                              hipStream_t stream) {
    const float* x   = (const float*)d_in[0];
    const int*   ei  = (const int*)d_in[1];      // int32 per harness contract
    const float* W1l = (const float*)d_in[2];
    const float* W1r = (const float*)d_in[3];
    const float* b1  = (const float*)d_in[4];
    const float* W2l = (const float*)d_in[5];
    const float* W2r = (const float*)d_in[6];
    const float* b2  = (const float*)d_in[7];
    float* out = (float*)d_out;

    const int M = in_sizes[0] / 128;
    const int E = in_sizes[1] / 2;
    const int NB = (M + 1023) / 1024;            // scan blocks (98 for M=100K)
    const size_t featBytes = (size_t)M * 128 * sizeof(float);
    const size_t al = 512;
    auto rup = [&](size_t b) { return (b + al - 1) & ~(al - 1); };

    char* ws = (char*)d_ws;
    size_t off = 0;
    int* cntHist  = (int*)(ws + off); off += rup((size_t)M * 4);
    int* rowStart = (int*)(ws + off); off += rup((size_t)(M + 1) * 4);
    int* cursor   = (int*)(ws + off); off += rup((size_t)M * 4);
    int* blockSum = (int*)(ws + off); off += rup(256 * 4);
    int* csr      = (int*)(ws + off); off += rup((size_t)E * 4);
    float* mean   = (float*)(ws + off); off += featBytes;
    float* h      = (float*)(ws + off); off += featBytes;
    float* wt1    = (float*)(ws + off); off += 256 * 128 * 4;
    float* wt2    = (float*)(ws + off);

    // 1. stacked weight transposes
    transpose_stack<<<128, 256, 0, stream>>>(W1l, W1r, wt1);
    transpose_stack<<<128, 256, 0, stream>>>(W2l, W2r, wt2);

    // 2. CSR build
    zero_kernel<<<128, 256, 0, stream>>>((float4*)cntHist, (long)(rup((size_t)M * 4) / 16));
    hist_kernel<<<(E + 255) / 256, 256, 0, stream>>>(ei, cntHist, E);
    scan1<<<NB, 256, 0, stream>>>(cntHist, blockSum, M);
    scan2<<<1, 256, 0, stream>>>(blockSum, NB);
    scan3<<<NB, 256, 0, stream>>>(cntHist, blockSum, rowStart, cursor, M);
    scatter_kernel<<<(E + 255) / 256, 256, 0, stream>>>(ei, cursor, csr, E);

    // 3. layer 1
    csr_aggregate<<<(M + 3) / 4, 256, 0, stream>>>(x, rowStart, csr, mean, M);
    sage_gemm<true><<<(M + 127) / 128, 256, 0, stream>>>(mean, x, wt1, b1, h, M);

    // 4. layer 2
    csr_aggregate<<<(M + 3) / 4, 256, 0, stream>>>(h, rowStart, csr, mean, M);
    sage_gemm<false><<<(M + 127) / 128, 256, 0, stream>>>(mean, h, wt2, b2, out, M);
}

// Round 6
// 407.690 us; speedup vs baseline: 3.4435x; 1.2611x over previous
//
#include <hip/hip_runtime.h>
#include <cstddef>

// ---------------------------------------------------------------------------
// GraphSAGE 2-layer (mean aggregator), fp32 in/out, MI355X.
//
// Round 5 -> 6: fp32 VALU GEMM (147us, VALUBusy 53%, MfmaUtil 0, 7.2M LDS
// conflicts) replaced by split-bf16 MFMA GEMM:
//   fp32 a = hi + lo (bf16 each, truncation split)
//   C = Ah@Wh + Ah@Wl + Al@Wh   (lo*lo dropped, ~2^-16 relative)
// using v_mfma_f32_16x16x32_bf16. W is pre-packed in fragment order (hi/lo)
// so B-fragments load straight from global (L2-resident, lane-contiguous).
// A is converted on the fly and staged in LDS in fragment-major order
// (lane-contiguous 16B ds_read_b128 = conflict-free).
//
// CSR-gather aggregation (round-5) unchanged.
// edge_index staged int32 (harness contract), [2][E]: src=ei[e], dst=ei[E+e].
// ---------------------------------------------------------------------------

typedef __attribute__((ext_vector_type(8))) short bf16x8;
typedef __attribute__((ext_vector_type(4))) float f32x4;
typedef __attribute__((ext_vector_type(4))) unsigned int u32x4;

__device__ __forceinline__ unsigned pack_hi(float x, float y) {
    return (__float_as_uint(x) >> 16) | (__float_as_uint(y) & 0xFFFF0000u);
}
__device__ __forceinline__ float hi_part(float x) {
    return __uint_as_float(__float_as_uint(x) & 0xFFFF0000u);
}

__global__ void zero_kernel(float4* __restrict__ p, long n4) {
    long i = (long)blockIdx.x * blockDim.x + threadIdx.x;
    long stride = (long)gridDim.x * blockDim.x;
    float4 z = {0.f, 0.f, 0.f, 0.f};
    for (; i < n4; i += stride) p[i] = z;
}

// ---------------- W fragment pre-pack ----------------
// out[ks][nf][lane][j] (bf16), ks=k-step of 32 (8), nf=16-col frag (8),
// lane 0..63, j 0..7.  col = nf*16+(lane&15); k2 = ks*32+(lane>>4)*8+j.
// Source: stacked K: k2<128 -> Wl[col][k2], else Wr[col][k2-128]. (W is
// [out_c][in_k] row-major = exactly the [col][k] orientation we need.)
__global__ void prep_wfrag(const float* __restrict__ Wl, const float* __restrict__ Wr,
                           unsigned short* __restrict__ hi, unsigned short* __restrict__ lo) {
    int t = blockIdx.x * 256 + threadIdx.x;      // 0..4095 = (ks*8+nf)*64+lane
    int lane = t & 63;
    int nf = (t >> 6) & 7;
    int col = nf * 16 + (lane & 15);
    int kb = (t >> 9) * 32 + (lane >> 4) * 8;    // k2 base for j=0
    unsigned hv[4], lv[4];
#pragma unroll
    for (int jj = 0; jj < 4; jj++) {
        int k0 = kb + 2 * jj, k1 = k0 + 1;
        float a0 = (k0 < 128) ? Wl[col * 128 + k0] : Wr[col * 128 + (k0 - 128)];
        float a1 = (k1 < 128) ? Wl[col * 128 + k1] : Wr[col * 128 + (k1 - 128)];
        hv[jj] = pack_hi(a0, a1);
        lv[jj] = pack_hi(a0 - hi_part(a0), a1 - hi_part(a1));
    }
    u32x4 h = {hv[0], hv[1], hv[2], hv[3]};
    u32x4 l = {lv[0], lv[1], lv[2], lv[3]};
    reinterpret_cast<u32x4*>(hi)[t] = h;
    reinterpret_cast<u32x4*>(lo)[t] = l;
}

// ---------------- CSR build ----------------

__global__ void hist_kernel(const int* __restrict__ ei, int* __restrict__ cnt, int E) {
    int e = blockIdx.x * 256 + threadIdx.x;
    if (e < E) atomicAdd(&cnt[ei[E + e]], 1);
}

__global__ void scan1(const int* __restrict__ cnt, int* __restrict__ blockSums, int M) {
    __shared__ int red[256];
    const int t = threadIdx.x;
    const int base = blockIdx.x * 1024 + t * 4;
    int s = 0;
#pragma unroll
    for (int i = 0; i < 4; i++) { int idx = base + i; if (idx < M) s += cnt[idx]; }
    red[t] = s; __syncthreads();
    for (int off = 128; off > 0; off >>= 1) {
        if (t < off) red[t] += red[t + off];
        __syncthreads();
    }
    if (t == 0) blockSums[blockIdx.x] = red[0];
}

__global__ void scan2(int* __restrict__ bs, int NB) {
    __shared__ int tmp[256];
    const int t = threadIdx.x;
    int v = (t < NB) ? bs[t] : 0;
    tmp[t] = v; __syncthreads();
    for (int off = 1; off < 256; off <<= 1) {
        int add = (t >= off) ? tmp[t - off] : 0;
        __syncthreads();
        tmp[t] += add;
        __syncthreads();
    }
    if (t < NB) bs[t] = tmp[t] - v;
}

__global__ void scan3(const int* __restrict__ cnt, const int* __restrict__ blockSums,
                      int* __restrict__ rowStart, int* __restrict__ cursor, int M) {
    __shared__ int tsum[256];
    const int t = threadIdx.x;
    const int base = blockIdx.x * 1024 + t * 4;
    int v[4];
#pragma unroll
    for (int i = 0; i < 4; i++) v[i] = (base + i < M) ? cnt[base + i] : 0;
    const int s = v[0] + v[1] + v[2] + v[3];
    tsum[t] = s; __syncthreads();
    for (int off = 1; off < 256; off <<= 1) {
        int add = (t >= off) ? tsum[t - off] : 0;
        __syncthreads();
        tsum[t] += add;
        __syncthreads();
    }
    int rs = blockSums[blockIdx.x] + (tsum[t] - s);
#pragma unroll
    for (int i = 0; i < 4; i++) {
        int idx = base + i;
        if (idx < M) {
            rowStart[idx] = rs;
            cursor[idx]   = rs;
            rs += v[i];
            if (idx == M - 1) rowStart[M] = rs;
        }
    }
}

__global__ void scatter_kernel(const int* __restrict__ ei, int* __restrict__ cursor,
                               int* __restrict__ csr, int E) {
    int e = blockIdx.x * 256 + threadIdx.x;
    if (e < E) {
        int d = ei[E + e];
        int pos = atomicAdd(&cursor[d], 1);
        csr[pos] = ei[e];
    }
}

// ---------------- mean aggregation (CSR gather) ----------------
__global__ void csr_aggregate(const float* __restrict__ feat,
                              const int* __restrict__ rowStart,
                              const int* __restrict__ csr,
                              float* __restrict__ mean, int M) {
    int n = blockIdx.x * (blockDim.x >> 6) + (threadIdx.x >> 6);
    if (n >= M) return;
    const int lane = threadIdx.x & 63;
    const int beg = rowStart[n], end = rowStart[n + 1];
    const int deg = end - beg;

    int myidx = (beg + lane < end) ? csr[beg + lane] : 0;
    float2 acc = {0.f, 0.f};
    const int K = deg < 64 ? deg : 64;
    for (int p = 0; p < K; p++) {
        int s = __shfl(myidx, p);
        const float2 v = *reinterpret_cast<const float2*>(&feat[(size_t)s * 128 + lane * 2]);
        acc.x += v.x; acc.y += v.y;
    }
    for (int q = beg + 64; q < end; q++) {
        int s = csr[q];
        const float2 v = *reinterpret_cast<const float2*>(&feat[(size_t)s * 128 + lane * 2]);
        acc.x += v.x; acc.y += v.y;
    }
    const float inv = 1.0f / fmaxf((float)deg, 1.0f);
    acc.x *= inv; acc.y *= inv;
    *reinterpret_cast<float2*>(&mean[(size_t)n * 128 + lane * 2]) = acc;
}

// ---------------- split-bf16 MFMA GEMM ----------------
// out = act([mean|self] @ W_stacked^T + bias), K=256.
// Block: 128 rows x 128 cols, 4 waves (2x2), wave = 64x64 = 4x4 frags of
// 16x16x32. 8 K-steps of 32. A staged in LDS fragment-major (hi/lo bf16),
// B fragments loaded from pre-packed global arrays (L2-resident).
template <bool RELU>
__global__ __launch_bounds__(256, 2)
void sage_gemm_mfma(const float* __restrict__ mean, const float* __restrict__ selfF,
                    const unsigned short* __restrict__ wHi,
                    const unsigned short* __restrict__ wLo,
                    const float* __restrict__ bias,
                    float* __restrict__ out, int M) {
    __shared__ unsigned short aHi[4096];   // [mf 0..7][lane 0..63][j 0..7]
    __shared__ unsigned short aLo[4096];

    const int tid  = threadIdx.x;
    const int lane = tid & 63;
    const int wid  = tid >> 6;
    const int wm   = wid >> 1;           // wave row (0/1)
    const int wn   = wid & 1;            // wave col (0/1)
    const int row0 = blockIdx.x * 128;

    // A staging: thread -> (row sr, k-half sh of 16 within the 32-wide step)
    const int sr = tid >> 1;             // 0..127
    const int sh = tid & 1;              // 0/1
    const int arow = row0 + sr;
    const bool av = arow < M;
    const float* mrow = mean  + (size_t)arow * 128 + sh * 16;
    const float* srow = selfF + (size_t)arow * 128 + sh * 16;
    // u32x4 slot for k-chunk kg=2*sh (8 bf16 = one frag j-run): frag-major
    const int wslot = (sr >> 4) * 64 + (sr & 15) + (2 * sh) * 16;

    f32x4 acc[4][4];
#pragma unroll
    for (int i = 0; i < 4; i++)
#pragma unroll
        for (int j = 0; j < 4; j++) acc[i][j] = {0.f, 0.f, 0.f, 0.f};

    float4 r[4], rn[4];
#pragma unroll
    for (int i = 0; i < 4; i++) { r[i] = {0.f,0.f,0.f,0.f}; rn[i] = {0.f,0.f,0.f,0.f}; }
    if (av) {
#pragma unroll
        for (int i = 0; i < 4; i++) r[i] = reinterpret_cast<const float4*>(mrow)[i];
    }

    const bf16x8* WH = reinterpret_cast<const bf16x8*>(wHi);
    const bf16x8* WL = reinterpret_cast<const bf16x8*>(wLo);
    const bf16x8* AH = reinterpret_cast<const bf16x8*>(aHi);
    const bf16x8* AL = reinterpret_cast<const bf16x8*>(aLo);

    for (int ks = 0; ks < 8; ks++) {
        // convert current regs -> packed bf16 hi/lo (reg-only, pre-barrier)
        u32x4 h0 = {pack_hi(r[0].x, r[0].y), pack_hi(r[0].z, r[0].w),
                    pack_hi(r[1].x, r[1].y), pack_hi(r[1].z, r[1].w)};
        u32x4 h1 = {pack_hi(r[2].x, r[2].y), pack_hi(r[2].z, r[2].w),
                    pack_hi(r[3].x, r[3].y), pack_hi(r[3].z, r[3].w)};
        u32x4 l0 = {pack_hi(r[0].x - hi_part(r[0].x), r[0].y - hi_part(r[0].y)),
                    pack_hi(r[0].z - hi_part(r[0].z), r[0].w - hi_part(r[0].w)),
                    pack_hi(r[1].x - hi_part(r[1].x), r[1].y - hi_part(r[1].y)),
                    pack_hi(r[1].z - hi_part(r[1].z), r[1].w - hi_part(r[1].w))};
        u32x4 l1 = {pack_hi(r[2].x - hi_part(r[2].x), r[2].y - hi_part(r[2].y)),
                    pack_hi(r[2].z - hi_part(r[2].z), r[2].w - hi_part(r[2].w)),
                    pack_hi(r[3].x - hi_part(r[3].x), r[3].y - hi_part(r[3].y)),
                    pack_hi(r[3].z - hi_part(r[3].z), r[3].w - hi_part(r[3].w))};

        if (ks) __syncthreads();             // previous tile fully consumed
        reinterpret_cast<u32x4*>(aHi)[wslot]      = h0;
        reinterpret_cast<u32x4*>(aHi)[wslot + 16] = h1;
        reinterpret_cast<u32x4*>(aLo)[wslot]      = l0;
        reinterpret_cast<u32x4*>(aLo)[wslot + 16] = l1;

        // prefetch next K-step's A regs (latency hides under MFMA phase)
        if (ks < 7) {
            const int k0n = (ks + 1) * 32;
            const float* src = (k0n < 128) ? (mrow + k0n) : (srow + (k0n - 128));
            if (av) {
#pragma unroll
                for (int i = 0; i < 4; i++) rn[i] = reinterpret_cast<const float4*>(src)[i];
            }
        }
        __syncthreads();                     // A tile ready

        // B fragments (global, L2-resident, lane-contiguous dwordx4)
        bf16x8 bh[4], bl[4], ah[4], al[4];
#pragma unroll
        for (int nfl = 0; nfl < 4; nfl++) {
            const int bidx = (ks * 8 + wn * 4 + nfl) * 64 + lane;
            bh[nfl] = WH[bidx];
            bl[nfl] = WL[bidx];
        }
#pragma unroll
        for (int mfl = 0; mfl < 4; mfl++) {
            const int aidx = (wm * 4 + mfl) * 64 + lane;
            ah[mfl] = AH[aidx];
            al[mfl] = AL[aidx];
        }
#pragma unroll
        for (int mfl = 0; mfl < 4; mfl++)
#pragma unroll
            for (int nfl = 0; nfl < 4; nfl++) {
                acc[mfl][nfl] = __builtin_amdgcn_mfma_f32_16x16x32_bf16(
                    ah[mfl], bh[nfl], acc[mfl][nfl], 0, 0, 0);
                acc[mfl][nfl] = __builtin_amdgcn_mfma_f32_16x16x32_bf16(
                    al[mfl], bh[nfl], acc[mfl][nfl], 0, 0, 0);
                acc[mfl][nfl] = __builtin_amdgcn_mfma_f32_16x16x32_bf16(
                    ah[mfl], bl[nfl], acc[mfl][nfl], 0, 0, 0);
            }
#pragma unroll
        for (int i = 0; i < 4; i++) r[i] = rn[i];
    }

    // epilogue: C/D layout col=lane&15, row=(lane>>4)*4+reg (m89-verified)
    const int colb = wn * 64 + (lane & 15);
    const int rowb = row0 + wm * 64 + ((lane >> 4) << 2);
#pragma unroll
    for (int nfl = 0; nfl < 4; nfl++) {
        const float bv = bias[colb + nfl * 16];
#pragma unroll
        for (int mfl = 0; mfl < 4; mfl++) {
#pragma unroll
            for (int q = 0; q < 4; q++) {
                const int row = rowb + mfl * 16 + q;
                if (row < M) {
                    float v = acc[mfl][nfl][q] + bv;
                    if (RELU) v = fmaxf(v, 0.0f);
                    out[(size_t)row * 128 + colb + nfl * 16] = v;
                }
            }
        }
    }
}

extern "C" void kernel_launch(void* const* d_in, const int* in_sizes, int n_in,
                              void* d_out, int out_size, void* d_ws, size_t ws_size,
                              hipStream_t stream) {
    const float* x   = (const float*)d_in[0];
    const int*   ei  = (const int*)d_in[1];      // int32 per harness contract
    const float* W1l = (const float*)d_in[2];
    const float* W1r = (const float*)d_in[3];
    const float* b1  = (const float*)d_in[4];
    const float* W2l = (const float*)d_in[5];
    const float* W2r = (const float*)d_in[6];
    const float* b2  = (const float*)d_in[7];
    float* out = (float*)d_out;

    const int M = in_sizes[0] / 128;
    const int E = in_sizes[1] / 2;
    const int NB = (M + 1023) / 1024;
    const size_t featBytes = (size_t)M * 128 * sizeof(float);
    const size_t al = 512;
    auto rup = [&](size_t b) { return (b + al - 1) & ~(al - 1); };

    char* ws = (char*)d_ws;
    size_t off = 0;
    int* cntHist  = (int*)(ws + off); off += rup((size_t)M * 4);
    int* rowStart = (int*)(ws + off); off += rup((size_t)(M + 1) * 4);
    int* cursor   = (int*)(ws + off); off += rup((size_t)M * 4);
    int* blockSum = (int*)(ws + off); off += rup(256 * 4);
    int* csr      = (int*)(ws + off); off += rup((size_t)E * 4);
    float* mean   = (float*)(ws + off); off += featBytes;
    float* h      = (float*)(ws + off); off += featBytes;
    unsigned short* w1hi = (unsigned short*)(ws + off); off += 256 * 128 * 2;
    unsigned short* w1lo = (unsigned short*)(ws + off); off += 256 * 128 * 2;
    unsigned short* w2hi = (unsigned short*)(ws + off); off += 256 * 128 * 2;
    unsigned short* w2lo = (unsigned short*)(ws + off); off += 256 * 128 * 2;

    // 1. W fragment pre-pack (hi/lo bf16, fragment order)
    prep_wfrag<<<16, 256, 0, stream>>>(W1l, W1r, w1hi, w1lo);
    prep_wfrag<<<16, 256, 0, stream>>>(W2l, W2r, w2hi, w2lo);

    // 2. CSR build
    zero_kernel<<<128, 256, 0, stream>>>((float4*)cntHist, (long)(rup((size_t)M * 4) / 16));
    hist_kernel<<<(E + 255) / 256, 256, 0, stream>>>(ei, cntHist, E);
    scan1<<<NB, 256, 0, stream>>>(cntHist, blockSum, M);
    scan2<<<1, 256, 0, stream>>>(blockSum, NB);
    scan3<<<NB, 256, 0, stream>>>(cntHist, blockSum, rowStart, cursor, M);
    scatter_kernel<<<(E + 255) / 256, 256, 0, stream>>>(ei, cursor, csr, E);

    // 3. layer 1
    csr_aggregate<<<(M + 3) / 4, 256, 0, stream>>>(x, rowStart, csr, mean, M);
    sage_gemm_mfma<true><<<(M + 127) / 128, 256, 0, stream>>>(mean, x, w1hi, w1lo, b1, h, M);

    // 4. layer 2
    csr_aggregate<<<(M + 3) / 4, 256, 0, stream>>>(h, rowStart, csr, mean, M);
    sage_gemm_mfma<false><<<(M + 127) / 128, 256, 0, stream>>>(mean, h, w2hi, w2lo, b2, out, M);
}

// Round 7
// 402.939 us; speedup vs baseline: 3.4841x; 1.0118x over previous
//
#include <hip/hip_runtime.h>
#include <cstddef>

// ---------------------------------------------------------------------------
// GraphSAGE 2-layer (mean aggregator), fp32 in/out, MI355X.
//
// Round 6 -> 7:
//  (a) csr_aggregate was latency-bound (73us, VALUBusy 19%, 35% BW): now
//      float4 loads with 32 lanes/row, two neighbors per wave concurrently
//      (upper/lower half-wave), pair-loop unrolled x2 -> 4x MLP.
//  (b) bf16 hi/lo split hoisted OUT of the GEMM K-loop: aggregate writes
//      mean as pre-split bf16 hi/lo planes; layer-1 GEMM epilogue writes h
//      as hi/lo planes (fp32 h never materialized). GEMM A-staging has zero
//      conversion VALU except layer-1 self=x (fp32, converted in prefetch
//      slot, overlapped with MFMA).
//
// GEMM: split-bf16 MFMA, C = Ah@Wh + Ah@Wl + Al@Wh (v_mfma_f32_16x16x32_bf16),
// W pre-packed in fragment order. CSR build unchanged.
// edge_index staged int32 (harness contract), [2][E]: src=ei[e], dst=ei[E+e].
// ---------------------------------------------------------------------------

typedef __attribute__((ext_vector_type(8))) short bf16x8;
typedef __attribute__((ext_vector_type(4))) float f32x4;
typedef __attribute__((ext_vector_type(4))) unsigned int u32x4;

__device__ __forceinline__ unsigned pack_hi(float x, float y) {
    return (__float_as_uint(x) >> 16) | (__float_as_uint(y) & 0xFFFF0000u);
}
__device__ __forceinline__ float hi_part(float x) {
    return __uint_as_float(__float_as_uint(x) & 0xFFFF0000u);
}
__device__ __forceinline__ float bf2f(unsigned short u) {
    return __uint_as_float(((unsigned)u) << 16);
}

__global__ void zero_kernel(float4* __restrict__ p, long n4) {
    long i = (long)blockIdx.x * blockDim.x + threadIdx.x;
    long stride = (long)gridDim.x * blockDim.x;
    float4 z = {0.f, 0.f, 0.f, 0.f};
    for (; i < n4; i += stride) p[i] = z;
}

// ---------------- W fragment pre-pack (hi/lo bf16, MFMA fragment order) ----
__global__ void prep_wfrag(const float* __restrict__ Wl, const float* __restrict__ Wr,
                           unsigned short* __restrict__ hi, unsigned short* __restrict__ lo) {
    int t = blockIdx.x * 256 + threadIdx.x;      // 0..4095 = (ks*8+nf)*64+lane
    int lane = t & 63;
    int nf = (t >> 6) & 7;
    int col = nf * 16 + (lane & 15);
    int kb = (t >> 9) * 32 + (lane >> 4) * 8;
    unsigned hv[4], lv[4];
#pragma unroll
    for (int jj = 0; jj < 4; jj++) {
        int k0 = kb + 2 * jj, k1 = k0 + 1;
        float a0 = (k0 < 128) ? Wl[col * 128 + k0] : Wr[col * 128 + (k0 - 128)];
        float a1 = (k1 < 128) ? Wl[col * 128 + k1] : Wr[col * 128 + (k1 - 128)];
        hv[jj] = pack_hi(a0, a1);
        lv[jj] = pack_hi(a0 - hi_part(a0), a1 - hi_part(a1));
    }
    u32x4 h = {hv[0], hv[1], hv[2], hv[3]};
    u32x4 l = {lv[0], lv[1], lv[2], lv[3]};
    reinterpret_cast<u32x4*>(hi)[t] = h;
    reinterpret_cast<u32x4*>(lo)[t] = l;
}

// ---------------- CSR build ----------------

__global__ void hist_kernel(const int* __restrict__ ei, int* __restrict__ cnt, int E) {
    int e = blockIdx.x * 256 + threadIdx.x;
    if (e < E) atomicAdd(&cnt[ei[E + e]], 1);
}

__global__ void scan1(const int* __restrict__ cnt, int* __restrict__ blockSums, int M) {
    __shared__ int red[256];
    const int t = threadIdx.x;
    const int base = blockIdx.x * 1024 + t * 4;
    int s = 0;
#pragma unroll
    for (int i = 0; i < 4; i++) { int idx = base + i; if (idx < M) s += cnt[idx]; }
    red[t] = s; __syncthreads();
    for (int off = 128; off > 0; off >>= 1) {
        if (t < off) red[t] += red[t + off];
        __syncthreads();
    }
    if (t == 0) blockSums[blockIdx.x] = red[0];
}

__global__ void scan2(int* __restrict__ bs, int NB) {
    __shared__ int tmp[256];
    const int t = threadIdx.x;
    int v = (t < NB) ? bs[t] : 0;
    tmp[t] = v; __syncthreads();
    for (int off = 1; off < 256; off <<= 1) {
        int add = (t >= off) ? tmp[t - off] : 0;
        __syncthreads();
        tmp[t] += add;
        __syncthreads();
    }
    if (t < NB) bs[t] = tmp[t] - v;
}

__global__ void scan3(const int* __restrict__ cnt, const int* __restrict__ blockSums,
                      int* __restrict__ rowStart, int* __restrict__ cursor, int M) {
    __shared__ int tsum[256];
    const int t = threadIdx.x;
    const int base = blockIdx.x * 1024 + t * 4;
    int v[4];
#pragma unroll
    for (int i = 0; i < 4; i++) v[i] = (base + i < M) ? cnt[base + i] : 0;
    const int s = v[0] + v[1] + v[2] + v[3];
    tsum[t] = s; __syncthreads();
    for (int off = 1; off < 256; off <<= 1) {
        int add = (t >= off) ? tsum[t - off] : 0;
        __syncthreads();
        tsum[t] += add;
        __syncthreads();
    }
    int rs = blockSums[blockIdx.x] + (tsum[t] - s);
#pragma unroll
    for (int i = 0; i < 4; i++) {
        int idx = base + i;
        if (idx < M) {
            rowStart[idx] = rs;
            cursor[idx]   = rs;
            rs += v[i];
            if (idx == M - 1) rowStart[M] = rs;
        }
    }
}

__global__ void scatter_kernel(const int* __restrict__ ei, int* __restrict__ cursor,
                               int* __restrict__ csr, int E) {
    int e = blockIdx.x * 256 + threadIdx.x;
    if (e < E) {
        int d = ei[E + e];
        int pos = atomicAdd(&cursor[d], 1);
        csr[pos] = ei[e];
    }
}

// ---------------- mean aggregation (CSR gather) ----------------
// One wave per node. 32 lanes cover a 128-float row (float4/lane); the two
// half-waves process neighbors 2p and 2p+1 concurrently; pair loop unrolled
// x2 (4 neighbors, 2 loads in flight per lane). Output: pre-split bf16
// hi/lo planes (half 0 writes hi, half 1 writes lo).
template <bool SPLIT_IN>
__global__ void csr_aggregate(const float* __restrict__ feat,
                              const unsigned short* __restrict__ fHi,
                              const unsigned short* __restrict__ fLo,
                              const int* __restrict__ rowStart,
                              const int* __restrict__ csr,
                              unsigned short* __restrict__ mHi,
                              unsigned short* __restrict__ mLo, int M) {
    int n = blockIdx.x * (blockDim.x >> 6) + (threadIdx.x >> 6);
    if (n >= M) return;
    const int lane = threadIdx.x & 63;
    const int half = lane >> 5;
    const int cl   = lane & 31;          // channels cl*4 .. cl*4+3
    const int beg = rowStart[n], end = rowStart[n + 1];
    const int deg = end - beg;

    int myidx = (beg + lane < end) ? csr[beg + lane] : 0;

    auto loadRow = [&](int s) -> float4 {
        if constexpr (!SPLIT_IN) {
            return *reinterpret_cast<const float4*>(feat + (size_t)s * 128 + cl * 4);
        } else {
            ushort4 hh = *reinterpret_cast<const ushort4*>(fHi + (size_t)s * 128 + cl * 4);
            ushort4 ll = *reinterpret_cast<const ushort4*>(fLo + (size_t)s * 128 + cl * 4);
            float4 v;
            v.x = bf2f(hh.x) + bf2f(ll.x);
            v.y = bf2f(hh.y) + bf2f(ll.y);
            v.z = bf2f(hh.z) + bf2f(ll.z);
            v.w = bf2f(hh.w) + bf2f(ll.w);
            return v;
        }
    };

    float4 a0 = {0.f, 0.f, 0.f, 0.f}, a1 = {0.f, 0.f, 0.f, 0.f};
    const int K  = deg < 64 ? deg : 64;
    const int NP = (K + 1) >> 1;         // pair iterations
    int p = 0;
    for (; p + 1 < NP; p += 2) {
        const int nb0 = 2 * p + half;
        const int nb1 = nb0 + 2;
        const int s0 = __shfl(myidx, nb0);
        const int s1 = __shfl(myidx, nb1);
        if (nb0 < K) { float4 v = loadRow(s0); a0.x += v.x; a0.y += v.y; a0.z += v.z; a0.w += v.w; }
        if (nb1 < K) { float4 v = loadRow(s1); a1.x += v.x; a1.y += v.y; a1.z += v.z; a1.w += v.w; }
    }
    if (p < NP) {
        const int nb = 2 * p + half;
        const int s = __shfl(myidx, nb);
        if (nb < K) { float4 v = loadRow(s); a0.x += v.x; a0.y += v.y; a0.z += v.z; a0.w += v.w; }
    }
    for (int q = beg + 64 + half; q < end; q += 2) {   // rare tail deg>64
        float4 v = loadRow(csr[q]);
        a0.x += v.x; a0.y += v.y; a0.z += v.z; a0.w += v.w;
    }
    a0.x += a1.x; a0.y += a1.y; a0.z += a1.z; a0.w += a1.w;

    // cross-half reduce: lane and lane^32 own the same channels
    a0.x += __shfl_xor(a0.x, 32);
    a0.y += __shfl_xor(a0.y, 32);
    a0.z += __shfl_xor(a0.z, 32);
    a0.w += __shfl_xor(a0.w, 32);

    const float inv = 1.0f / fmaxf((float)deg, 1.0f);
    float m[4] = {a0.x * inv, a0.y * inv, a0.z * inv, a0.w * inv};

    ushort4 st;
    if (half == 0) {     // hi plane
        st.x = __float_as_uint(m[0]) >> 16;
        st.y = __float_as_uint(m[1]) >> 16;
        st.z = __float_as_uint(m[2]) >> 16;
        st.w = __float_as_uint(m[3]) >> 16;
        *reinterpret_cast<ushort4*>(mHi + (size_t)n * 128 + cl * 4) = st;
    } else {             // lo plane
        st.x = __float_as_uint(m[0] - hi_part(m[0])) >> 16;
        st.y = __float_as_uint(m[1] - hi_part(m[1])) >> 16;
        st.z = __float_as_uint(m[2] - hi_part(m[2])) >> 16;
        st.w = __float_as_uint(m[3] - hi_part(m[3])) >> 16;
        *reinterpret_cast<ushort4*>(mLo + (size_t)n * 128 + cl * 4) = st;
    }
}

// ---------------- split-bf16 MFMA GEMM ----------------
// out = act([mean|self] @ W_stacked^T + bias), K=256.
// Block 128x128, 4 waves (2x2), wave = 4x4 frags of 16x16x32, 8 K-steps.
// A staged in LDS fragment-major from PRE-SPLIT hi/lo planes (mean always;
// self pre-split unless SELF_F32). SPLIT_OUT: epilogue writes hi/lo planes.
template <bool RELU, bool SELF_F32, bool SPLIT_OUT>
__global__ __launch_bounds__(256, 2)
void sage_gemm_mfma(const unsigned short* __restrict__ mHi,
                    const unsigned short* __restrict__ mLo,
                    const float* __restrict__ selfF,
                    const unsigned short* __restrict__ sHi,
                    const unsigned short* __restrict__ sLo,
                    const unsigned short* __restrict__ wHi,
                    const unsigned short* __restrict__ wLo,
                    const float* __restrict__ bias,
                    float* __restrict__ outF,
                    unsigned short* __restrict__ outHi,
                    unsigned short* __restrict__ outLo,
                    int M) {
    __shared__ unsigned short aHi[4096];   // [mf 0..7][lane 0..63][j 0..7]
    __shared__ unsigned short aLo[4096];

    const int tid  = threadIdx.x;
    const int lane = tid & 63;
    const int wid  = tid >> 6;
    const int wm   = wid >> 1;
    const int wn   = wid & 1;
    const int row0 = blockIdx.x * 128;

    const int sr = tid >> 1;             // staging row 0..127
    const int sh = tid & 1;              // k-half (16 elems)
    const int arow = row0 + sr;
    const bool av = arow < M;
    const size_t rb = (size_t)arow * 128 + sh * 16;
    const int wslot = (sr >> 4) * 64 + (sr & 15) + (2 * sh) * 16;

    f32x4 acc[4][4];
#pragma unroll
    for (int i = 0; i < 4; i++)
#pragma unroll
        for (int j = 0; j < 4; j++) acc[i][j] = {0.f, 0.f, 0.f, 0.f};

    u32x4 h0, h1, l0, l1, nh0, nh1, nl0, nl1;

    auto loadA = [&](int ks, u32x4& H0, u32x4& H1, u32x4& L0, u32x4& L1) {
        if (!av) { H0 = H1 = L0 = L1 = (u32x4){0u, 0u, 0u, 0u}; return; }
        const int k0 = ks * 32;
        if (k0 < 128) {
            const unsigned short* ph = mHi + rb + k0;
            const unsigned short* pl = mLo + rb + k0;
            H0 = *reinterpret_cast<const u32x4*>(ph);
            H1 = *reinterpret_cast<const u32x4*>(ph + 8);
            L0 = *reinterpret_cast<const u32x4*>(pl);
            L1 = *reinterpret_cast<const u32x4*>(pl + 8);
        } else if constexpr (!SELF_F32) {
            const unsigned short* ph = sHi + rb + (k0 - 128);
            const unsigned short* pl = sLo + rb + (k0 - 128);
            H0 = *reinterpret_cast<const u32x4*>(ph);
            H1 = *reinterpret_cast<const u32x4*>(ph + 8);
            L0 = *reinterpret_cast<const u32x4*>(pl);
            L1 = *reinterpret_cast<const u32x4*>(pl + 8);
        } else {
            const float* ps = selfF + rb + (k0 - 128);
            float4 r0 = reinterpret_cast<const float4*>(ps)[0];
            float4 r1 = reinterpret_cast<const float4*>(ps)[1];
            float4 r2 = reinterpret_cast<const float4*>(ps)[2];
            float4 r3 = reinterpret_cast<const float4*>(ps)[3];
            H0 = (u32x4){pack_hi(r0.x, r0.y), pack_hi(r0.z, r0.w),
                         pack_hi(r1.x, r1.y), pack_hi(r1.z, r1.w)};
            H1 = (u32x4){pack_hi(r2.x, r2.y), pack_hi(r2.z, r2.w),
                         pack_hi(r3.x, r3.y), pack_hi(r3.z, r3.w)};
            L0 = (u32x4){pack_hi(r0.x - hi_part(r0.x), r0.y - hi_part(r0.y)),
                         pack_hi(r0.z - hi_part(r0.z), r0.w - hi_part(r0.w)),
                         pack_hi(r1.x - hi_part(r1.x), r1.y - hi_part(r1.y)),
                         pack_hi(r1.z - hi_part(r1.z), r1.w - hi_part(r1.w))};
            L1 = (u32x4){pack_hi(r2.x - hi_part(r2.x), r2.y - hi_part(r2.y)),
                         pack_hi(r2.z - hi_part(r2.z), r2.w - hi_part(r2.w)),
                         pack_hi(r3.x - hi_part(r3.x), r3.y - hi_part(r3.y)),
                         pack_hi(r3.z - hi_part(r3.z), r3.w - hi_part(r3.w))};
        }
    };

    const bf16x8* WH = reinterpret_cast<const bf16x8*>(wHi);
    const bf16x8* WL = reinterpret_cast<const bf16x8*>(wLo);
    const bf16x8* AH = reinterpret_cast<const bf16x8*>(aHi);
    const bf16x8* AL = reinterpret_cast<const bf16x8*>(aLo);

    loadA(0, h0, h1, l0, l1);
    for (int ks = 0; ks < 8; ks++) {
        if (ks) __syncthreads();
        reinterpret_cast<u32x4*>(aHi)[wslot]      = h0;
        reinterpret_cast<u32x4*>(aHi)[wslot + 16] = h1;
        reinterpret_cast<u32x4*>(aLo)[wslot]      = l0;
        reinterpret_cast<u32x4*>(aLo)[wslot + 16] = l1;
        if (ks < 7) loadA(ks + 1, nh0, nh1, nl0, nl1);
        __syncthreads();

        bf16x8 bh[4], bl[4], ah[4], al[4];
#pragma unroll
        for (int nfl = 0; nfl < 4; nfl++) {
            const int bidx = (ks * 8 + wn * 4 + nfl) * 64 + lane;
            bh[nfl] = WH[bidx];
            bl[nfl] = WL[bidx];
        }
#pragma unroll
        for (int mfl = 0; mfl < 4; mfl++) {
            const int aidx = (wm * 4 + mfl) * 64 + lane;
            ah[mfl] = AH[aidx];
            al[mfl] = AL[aidx];
        }
#pragma unroll
        for (int mfl = 0; mfl < 4; mfl++)
#pragma unroll
            for (int nfl = 0; nfl < 4; nfl++) {
                acc[mfl][nfl] = __builtin_amdgcn_mfma_f32_16x16x32_bf16(
                    ah[mfl], bh[nfl], acc[mfl][nfl], 0, 0, 0);
                acc[mfl][nfl] = __builtin_amdgcn_mfma_f32_16x16x32_bf16(
                    al[mfl], bh[nfl], acc[mfl][nfl], 0, 0, 0);
                acc[mfl][nfl] = __builtin_amdgcn_mfma_f32_16x16x32_bf16(
                    ah[mfl], bl[nfl], acc[mfl][nfl], 0, 0, 0);
            }
        h0 = nh0; h1 = nh1; l0 = nl0; l1 = nl1;
    }

    // epilogue: C/D layout col=lane&15, row=(lane>>4)*4+reg (m89-verified)
    const int colb = wn * 64 + (lane & 15);
    const int rowb = row0 + wm * 64 + ((lane >> 4) << 2);
#pragma unroll
    for (int nfl = 0; nfl < 4; nfl++) {
        const float bv = bias[colb + nfl * 16];
#pragma unroll
        for (int mfl = 0; mfl < 4; mfl++) {
#pragma unroll
            for (int q = 0; q < 4; q++) {
                const int row = rowb + mfl * 16 + q;
                if (row < M) {
                    float v = acc[mfl][nfl][q] + bv;
                    if (RELU) v = fmaxf(v, 0.0f);
                    const size_t idx = (size_t)row * 128 + colb + nfl * 16;
                    if constexpr (!SPLIT_OUT) {
                        outF[idx] = v;
                    } else {
                        const unsigned u = __float_as_uint(v);
                        outHi[idx] = (unsigned short)(u >> 16);
                        const float fh = __uint_as_float(u & 0xFFFF0000u);
                        outLo[idx] = (unsigned short)(__float_as_uint(v - fh) >> 16);
                    }
                }
            }
        }
    }
}

extern "C" void kernel_launch(void* const* d_in, const int* in_sizes, int n_in,
                              void* d_out, int out_size, void* d_ws, size_t ws_size,
                              hipStream_t stream) {
    const float* x   = (const float*)d_in[0];
    const int*   ei  = (const int*)d_in[1];      // int32 per harness contract
    const float* W1l = (const float*)d_in[2];
    const float* W1r = (const float*)d_in[3];
    const float* b1  = (const float*)d_in[4];
    const float* W2l = (const float*)d_in[5];
    const float* W2r = (const float*)d_in[6];
    const float* b2  = (const float*)d_in[7];
    float* out = (float*)d_out;

    const int M = in_sizes[0] / 128;
    const int E = in_sizes[1] / 2;
    const int NB = (M + 1023) / 1024;
    const size_t planeBytes = (size_t)M * 128 * sizeof(unsigned short);  // bf16 plane
    const size_t al = 512;
    auto rup = [&](size_t b) { return (b + al - 1) & ~(al - 1); };

    char* ws = (char*)d_ws;
    size_t off = 0;
    int* cntHist  = (int*)(ws + off); off += rup((size_t)M * 4);
    int* rowStart = (int*)(ws + off); off += rup((size_t)(M + 1) * 4);
    int* cursor   = (int*)(ws + off); off += rup((size_t)M * 4);
    int* blockSum = (int*)(ws + off); off += rup(256 * 4);
    int* csr      = (int*)(ws + off); off += rup((size_t)E * 4);
    unsigned short* meanHi = (unsigned short*)(ws + off); off += rup(planeBytes);
    unsigned short* meanLo = (unsigned short*)(ws + off); off += rup(planeBytes);
    unsigned short* hHi    = (unsigned short*)(ws + off); off += rup(planeBytes);
    unsigned short* hLo    = (unsigned short*)(ws + off); off += rup(planeBytes);
    unsigned short* w1hi = (unsigned short*)(ws + off); off += 256 * 128 * 2;
    unsigned short* w1lo = (unsigned short*)(ws + off); off += 256 * 128 * 2;
    unsigned short* w2hi = (unsigned short*)(ws + off); off += 256 * 128 * 2;
    unsigned short* w2lo = (unsigned short*)(ws + off); off += 256 * 128 * 2;

    // 1. W fragment pre-pack
    prep_wfrag<<<16, 256, 0, stream>>>(W1l, W1r, w1hi, w1lo);
    prep_wfrag<<<16, 256, 0, stream>>>(W2l, W2r, w2hi, w2lo);

    // 2. CSR build
    zero_kernel<<<128, 256, 0, stream>>>((float4*)cntHist, (long)(rup((size_t)M * 4) / 16));
    hist_kernel<<<(E + 255) / 256, 256, 0, stream>>>(ei, cntHist, E);
    scan1<<<NB, 256, 0, stream>>>(cntHist, blockSum, M);
    scan2<<<1, 256, 0, stream>>>(blockSum, NB);
    scan3<<<NB, 256, 0, stream>>>(cntHist, blockSum, rowStart, cursor, M);
    scatter_kernel<<<(E + 255) / 256, 256, 0, stream>>>(ei, cursor, csr, E);

    // 3. layer 1: aggregate x (fp32 in) -> mean hi/lo; GEMM -> h hi/lo (relu)
    csr_aggregate<false><<<(M + 3) / 4, 256, 0, stream>>>(
        x, nullptr, nullptr, rowStart, csr, meanHi, meanLo, M);
    sage_gemm_mfma<true, true, true><<<(M + 127) / 128, 256, 0, stream>>>(
        meanHi, meanLo, x, nullptr, nullptr, w1hi, w1lo, b1, nullptr, hHi, hLo, M);

    // 4. layer 2: aggregate h (hi/lo in) -> mean hi/lo; GEMM -> out fp32
    csr_aggregate<true><<<(M + 3) / 4, 256, 0, stream>>>(
        nullptr, hHi, hLo, rowStart, csr, meanHi, meanLo, M);
    sage_gemm_mfma<false, false, false><<<(M + 127) / 128, 256, 0, stream>>>(
        meanHi, meanLo, nullptr, hHi, hLo, w2hi, w2lo, b2, out, nullptr, nullptr, M);
}